// Round 1
// baseline (2629.897 us; speedup 1.0000x reference)
//
#include <hip/hip_runtime.h>
#include <math.h>

// Problem constants (fixed by the reference)
constexpr int N  = 64000;
constexpr int E  = 1024000;
constexpr int D  = 512;
constexpr int KT = 2048;
constexpr int B  = 16;
constexpr int NP = 4000;   // nodes per graph
constexpr int KP = 128;    // clusters per graph

// ---------------------------------------------------------------------------
// CSR / bucket build
// ---------------------------------------------------------------------------
__global__ void k_count(const int* __restrict__ src, const int* __restrict__ dst,
                        int* __restrict__ deg, int* __restrict__ bcnt) {
    int e = blockIdx.x * blockDim.x + threadIdx.x;
    if (e >= E) return;
    int s = src[e], d = dst[e];
    atomicAdd(&deg[d], 1);
    atomicAdd(&bcnt[(s / NP) * B + d / NP], 1);
}

__global__ void k_scan(const int* __restrict__ deg, int* __restrict__ rowstart,
                       const int* __restrict__ bcnt, int* __restrict__ boff) {
    __shared__ int wsum[16];
    __shared__ int carry;
    int t = threadIdx.x, lane = t & 63, w = t >> 6;
    if (t == 0) carry = 0;
    __syncthreads();
    for (int base = 0; base < N; base += 1024) {
        int v = (base + t < N) ? deg[base + t] : 0;
        int x = v;
        #pragma unroll
        for (int off = 1; off < 64; off <<= 1) {
            int y = __shfl_up(x, off);
            if (lane >= off) x += y;
        }
        if (lane == 63) wsum[w] = x;
        __syncthreads();
        if (t < 16) {
            int s = wsum[t];
            #pragma unroll
            for (int off = 1; off < 16; off <<= 1) {
                int y = __shfl_up(s, off);
                if (t >= off) s += y;
            }
            wsum[t] = s;
        }
        __syncthreads();
        int prev = carry + ((w > 0) ? wsum[w - 1] : 0);
        if (base + t < N) rowstart[base + t] = prev + x - v;
        __syncthreads();
        if (t == 0) carry += wsum[15];
        __syncthreads();
    }
    if (t == 0) {
        rowstart[N] = carry;
        int s = 0;
        for (int i = 0; i < 256; ++i) { boff[i] = s; s += bcnt[i]; }
        boff[256] = s;
    }
}

__global__ void k_fill(const int* __restrict__ src, const int* __restrict__ dst,
                       const int* __restrict__ rowstart, int* __restrict__ cursor,
                       const int* __restrict__ boff, int* __restrict__ bcur,
                       int* __restrict__ csr, int* __restrict__ bsrc,
                       int* __restrict__ bdst) {
    int e = blockIdx.x * blockDim.x + threadIdx.x;
    if (e >= E) return;
    int s = src[e], d = dst[e];
    int slot = atomicAdd(&cursor[d], 1);
    csr[rowstart[d] + slot] = s;
    int g = (s / NP) * B + d / NP;
    int p = atomicAdd(&bcur[g], 1);
    bsrc[boff[g] + p] = s;
    bdst[boff[g] + p] = d;
}

// ---------------------------------------------------------------------------
// xplus = feat + mean_neighbors(feat)   (one wave per node, float4 lanes)
// ---------------------------------------------------------------------------
__global__ __launch_bounds__(256) void k_agg(const float* __restrict__ feat,
                                             const int* __restrict__ rowstart,
                                             const int* __restrict__ csr,
                                             float* __restrict__ xplus) {
    int w = threadIdx.x >> 6, lane = threadIdx.x & 63;
    int node = blockIdx.x * 4 + w;
    int r0 = rowstart[node], r1 = rowstart[node + 1];
    const float4* f4 = (const float4*)feat;
    float4 a0 = {0.f, 0.f, 0.f, 0.f}, a1 = {0.f, 0.f, 0.f, 0.f};
    for (int j = r0; j < r1; ++j) {
        int s = csr[j];
        const float4* row = f4 + (size_t)s * (D / 4);
        float4 v0 = row[lane], v1 = row[64 + lane];
        a0.x += v0.x; a0.y += v0.y; a0.z += v0.z; a0.w += v0.w;
        a1.x += v1.x; a1.y += v1.y; a1.z += v1.z; a1.w += v1.w;
    }
    float inv = 1.0f / fmaxf((float)(r1 - r0), 1.0f);
    const float4* self = f4 + (size_t)node * (D / 4);
    float4 s0 = self[lane], s1 = self[64 + lane];
    float4 o0 = {s0.x + a0.x * inv, s0.y + a0.y * inv, s0.z + a0.z * inv, s0.w + a0.w * inv};
    float4 o1 = {s1.x + a1.x * inv, s1.y + a1.y * inv, s1.z + a1.z * inv, s1.w + a1.w * inv};
    float4* x4 = (float4*)xplus + (size_t)node * (D / 4);
    x4[lane] = o0;
    x4[64 + lane] = o1;
}

// ---------------------------------------------------------------------------
// hfeat = relu(xplus @ W_feat + b_feat)   [64000,512]x[512,512]
// 128x128 tile, 256 thr, 8x8 micro (2x2 quadrants of 4x4)
// ---------------------------------------------------------------------------
__global__ __launch_bounds__(256) void k_gemm_feat(const float* __restrict__ Xp,
                                                   const float* __restrict__ W,
                                                   const float* __restrict__ bias,
                                                   float* __restrict__ Hf) {
    __shared__ float As[16][132];
    __shared__ float Bs[16][132];
    int t = threadIdx.x, tx = t & 15, ty = t >> 4;
    int row0 = blockIdx.x * 128, col0 = blockIdx.y * 128;
    float acc[2][2][4][4] = {};
    for (int k0 = 0; k0 < D; k0 += 16) {
        #pragma unroll
        for (int i = 0; i < 2; ++i) {
            int idx = t + i * 256;
            int r = idx >> 2, c4 = (idx & 3) << 2;
            float4 v = *(const float4*)&Xp[(size_t)(row0 + r) * D + k0 + c4];
            As[c4 + 0][r] = v.x; As[c4 + 1][r] = v.y;
            As[c4 + 2][r] = v.z; As[c4 + 3][r] = v.w;
        }
        #pragma unroll
        for (int i = 0; i < 2; ++i) {
            int idx = t + i * 256;
            int kr = idx >> 5, c4 = (idx & 31) << 2;
            *(float4*)&Bs[kr][c4] = *(const float4*)&W[(size_t)(k0 + kr) * 512 + col0 + c4];
        }
        __syncthreads();
        #pragma unroll
        for (int kk = 0; kk < 16; ++kk) {
            float4 a0 = *(const float4*)&As[kk][ty * 4];
            float4 a1 = *(const float4*)&As[kk][64 + ty * 4];
            float4 b0 = *(const float4*)&Bs[kk][tx * 4];
            float4 b1 = *(const float4*)&Bs[kk][64 + tx * 4];
            float av[2][4] = {{a0.x, a0.y, a0.z, a0.w}, {a1.x, a1.y, a1.z, a1.w}};
            float bv[2][4] = {{b0.x, b0.y, b0.z, b0.w}, {b1.x, b1.y, b1.z, b1.w}};
            #pragma unroll
            for (int qa = 0; qa < 2; ++qa)
                #pragma unroll
                for (int i = 0; i < 4; ++i)
                    #pragma unroll
                    for (int qb = 0; qb < 2; ++qb)
                        #pragma unroll
                        for (int j = 0; j < 4; ++j)
                            acc[qa][qb][i][j] = fmaf(av[qa][i], bv[qb][j], acc[qa][qb][i][j]);
        }
        __syncthreads();
    }
    #pragma unroll
    for (int qa = 0; qa < 2; ++qa)
        #pragma unroll
        for (int i = 0; i < 4; ++i) {
            int row = row0 + qa * 64 + ty * 4 + i;
            #pragma unroll
            for (int qb = 0; qb < 2; ++qb) {
                int col = col0 + qb * 64 + tx * 4;
                float4 o;
                o.x = fmaxf(acc[qa][qb][i][0] + bias[col + 0], 0.f);
                o.y = fmaxf(acc[qa][qb][i][1] + bias[col + 1], 0.f);
                o.z = fmaxf(acc[qa][qb][i][2] + bias[col + 2], 0.f);
                o.w = fmaxf(acc[qa][qb][i][3] + bias[col + 3], 0.f);
                *(float4*)&Hf[(size_t)row * D + col] = o;
            }
        }
}

// ---------------------------------------------------------------------------
// sc = softmax(relu(xplus @ W_pool[:, g*128:+128] + b_pool), per-row over 128)
// Only in-graph columns matter (masked softmax reduces to this).
// Softmax fused: row lives in 16 consecutive lanes -> shfl_xor reduce.
// ---------------------------------------------------------------------------
__global__ __launch_bounds__(256) void k_gemm_pool(const float* __restrict__ Xp,
                                                   const float* __restrict__ Wp,
                                                   const float* __restrict__ bp,
                                                   float* __restrict__ sc) {
    __shared__ float As[16][132];
    __shared__ float Bs[16][132];
    int t = threadIdx.x, tx = t & 15, ty = t >> 4;
    int bm = blockIdx.x;      // 0..31
    int g  = blockIdx.y;      // 0..15
    int row0 = g * NP + bm * 128;
    int nrows = NP - bm * 128; if (nrows > 128) nrows = 128;
    int col0 = g * KP;
    float acc[2][2][4][4] = {};
    for (int k0 = 0; k0 < D; k0 += 16) {
        #pragma unroll
        for (int i = 0; i < 2; ++i) {
            int idx = t + i * 256;
            int r = idx >> 2, c4 = (idx & 3) << 2;
            float4 v = {0.f, 0.f, 0.f, 0.f};
            if (r < nrows) v = *(const float4*)&Xp[(size_t)(row0 + r) * D + k0 + c4];
            As[c4 + 0][r] = v.x; As[c4 + 1][r] = v.y;
            As[c4 + 2][r] = v.z; As[c4 + 3][r] = v.w;
        }
        #pragma unroll
        for (int i = 0; i < 2; ++i) {
            int idx = t + i * 256;
            int kr = idx >> 5, c4 = (idx & 31) << 2;
            *(float4*)&Bs[kr][c4] = *(const float4*)&Wp[(size_t)(k0 + kr) * KT + col0 + c4];
        }
        __syncthreads();
        #pragma unroll
        for (int kk = 0; kk < 16; ++kk) {
            float4 a0 = *(const float4*)&As[kk][ty * 4];
            float4 a1 = *(const float4*)&As[kk][64 + ty * 4];
            float4 b0 = *(const float4*)&Bs[kk][tx * 4];
            float4 b1 = *(const float4*)&Bs[kk][64 + tx * 4];
            float av[2][4] = {{a0.x, a0.y, a0.z, a0.w}, {a1.x, a1.y, a1.z, a1.w}};
            float bv[2][4] = {{b0.x, b0.y, b0.z, b0.w}, {b1.x, b1.y, b1.z, b1.w}};
            #pragma unroll
            for (int qa = 0; qa < 2; ++qa)
                #pragma unroll
                for (int i = 0; i < 4; ++i)
                    #pragma unroll
                    for (int qb = 0; qb < 2; ++qb)
                        #pragma unroll
                        for (int j = 0; j < 4; ++j)
                            acc[qa][qb][i][j] = fmaf(av[qa][i], bv[qb][j], acc[qa][qb][i][j]);
        }
        __syncthreads();
    }
    // epilogue: bias + relu + row softmax (row = 16 lanes x 8 cols) + store
    #pragma unroll
    for (int qa = 0; qa < 2; ++qa)
        #pragma unroll
        for (int i = 0; i < 4; ++i) {
            float v[2][4];
            #pragma unroll
            for (int qb = 0; qb < 2; ++qb)
                #pragma unroll
                for (int j = 0; j < 4; ++j)
                    v[qb][j] = fmaxf(acc[qa][qb][i][j] + bp[col0 + qb * 64 + tx * 4 + j], 0.f);
            float m = v[0][0];
            #pragma unroll
            for (int qb = 0; qb < 2; ++qb)
                #pragma unroll
                for (int j = 0; j < 4; ++j) m = fmaxf(m, v[qb][j]);
            #pragma unroll
            for (int off = 1; off < 16; off <<= 1) m = fmaxf(m, __shfl_xor(m, off));
            float ssum = 0.f;
            #pragma unroll
            for (int qb = 0; qb < 2; ++qb)
                #pragma unroll
                for (int j = 0; j < 4; ++j) { v[qb][j] = __expf(v[qb][j] - m); ssum += v[qb][j]; }
            #pragma unroll
            for (int off = 1; off < 16; off <<= 1) ssum += __shfl_xor(ssum, off);
            float inv = 1.0f / ssum;
            int r = qa * 64 + ty * 4 + i;
            if (r < nrows) {
                int node = row0 + r;
                float4 o0 = {v[0][0] * inv, v[0][1] * inv, v[0][2] * inv, v[0][3] * inv};
                float4 o1 = {v[1][0] * inv, v[1][1] * inv, v[1][2] * inv, v[1][3] * inv};
                *(float4*)&sc[(size_t)node * KP + tx * 4] = o0;
                *(float4*)&sc[(size_t)node * KP + 64 + tx * 4] = o1;
            }
        }
}

// ---------------------------------------------------------------------------
// h = s^T @ hfeat, per graph: [128 x 512] = sum over 4000 nodes. split-K x4.
// ---------------------------------------------------------------------------
__global__ __launch_bounds__(256) void k_h(const float* __restrict__ sc,
                                           const float* __restrict__ hf,
                                           float* __restrict__ outH) {
    __shared__ float Ss[16][132];   // [node_k][cluster 0..127]
    __shared__ float Hs[16][68];    // [node_k][dim col 0..63]
    int t = threadIdx.x, tx = t & 15, ty = t >> 4;
    int g  = blockIdx.x;   // 16
    int bn = blockIdx.y;   // 8
    int kz = blockIdx.z;   // 4
    int col0 = bn * 64;
    int i0 = g * NP + kz * 1000, i1 = i0 + 1000;
    float acc[2][4][4] = {};
    for (int kb = i0; kb < i1; kb += 16) {
        #pragma unroll
        for (int i = 0; i < 2; ++i) {
            int idx = t + i * 256;
            int r = idx >> 5, c4 = (idx & 31) << 2;
            int node = kb + r;
            float4 v = {0.f, 0.f, 0.f, 0.f};
            if (node < i1) v = *(const float4*)&sc[(size_t)node * KP + c4];
            *(float4*)&Ss[r][c4] = v;
        }
        {
            int r = t >> 4, c4 = (t & 15) << 2;
            int node = kb + r;
            float4 v = {0.f, 0.f, 0.f, 0.f};
            if (node < i1) v = *(const float4*)&hf[(size_t)node * D + col0 + c4];
            *(float4*)&Hs[r][c4] = v;
        }
        __syncthreads();
        #pragma unroll
        for (int kk = 0; kk < 16; ++kk) {
            float4 a0 = *(const float4*)&Ss[kk][ty * 4];
            float4 a1 = *(const float4*)&Ss[kk][64 + ty * 4];
            float4 b  = *(const float4*)&Hs[kk][tx * 4];
            float av[2][4] = {{a0.x, a0.y, a0.z, a0.w}, {a1.x, a1.y, a1.z, a1.w}};
            float bv[4] = {b.x, b.y, b.z, b.w};
            #pragma unroll
            for (int qa = 0; qa < 2; ++qa)
                #pragma unroll
                for (int i = 0; i < 4; ++i)
                    #pragma unroll
                    for (int j = 0; j < 4; ++j)
                        acc[qa][i][j] = fmaf(av[qa][i], bv[j], acc[qa][i][j]);
        }
        __syncthreads();
    }
    #pragma unroll
    for (int qa = 0; qa < 2; ++qa)
        #pragma unroll
        for (int i = 0; i < 4; ++i) {
            int row = g * KP + qa * 64 + ty * 4 + i;
            #pragma unroll
            for (int j = 0; j < 4; ++j)
                atomicAdd(&outH[(size_t)row * D + col0 + tx * 4 + j], acc[qa][i][j]);
        }
}

// ---------------------------------------------------------------------------
// adj_new = sum over edges of outer(sc[src], sc[dst]), bucketed by (gs,gd).
// One block per (bucket, half). 128x128 f32 acc in regs (8x8/thread).
// ---------------------------------------------------------------------------
constexpr int ADJ_SPLIT = 2;
__global__ __launch_bounds__(256) void k_adj(const float* __restrict__ sc,
                                             const int* __restrict__ bsrc,
                                             const int* __restrict__ bdst,
                                             const int* __restrict__ boff,
                                             float* __restrict__ outA) {
    __shared__ float Us[16][132];
    __shared__ float Vs[16][132];
    int t = threadIdx.x, tx = t & 15, ty = t >> 4;
    int b = blockIdx.x;           // 0..255
    int half = blockIdx.y;        // 0..ADJ_SPLIT-1
    int gs = b >> 4, gd = b & 15;
    int e0 = boff[b], e1 = boff[b + 1];
    int cnt = e1 - e0;
    int s0 = e0 + (int)(((long long)cnt * half) / ADJ_SPLIT);
    int s1 = e0 + (int)(((long long)cnt * (half + 1)) / ADJ_SPLIT);
    float acc[2][2][4][4] = {};
    for (int kb = s0; kb < s1; kb += 16) {
        #pragma unroll
        for (int i = 0; i < 2; ++i) {
            int idx = t + i * 256;
            int r = idx >> 5, c4 = (idx & 31) << 2;
            int eb = kb + r;
            float4 u = {0.f, 0.f, 0.f, 0.f}, v = {0.f, 0.f, 0.f, 0.f};
            if (eb < s1) {
                int sn = bsrc[eb], dn = bdst[eb];
                u = *(const float4*)&sc[(size_t)sn * KP + c4];
                v = *(const float4*)&sc[(size_t)dn * KP + c4];
            }
            *(float4*)&Us[r][c4] = u;
            *(float4*)&Vs[r][c4] = v;
        }
        __syncthreads();
        #pragma unroll
        for (int kk = 0; kk < 16; ++kk) {
            float4 a0 = *(const float4*)&Us[kk][ty * 4];
            float4 a1 = *(const float4*)&Us[kk][64 + ty * 4];
            float4 b0 = *(const float4*)&Vs[kk][tx * 4];
            float4 b1 = *(const float4*)&Vs[kk][64 + tx * 4];
            float av[2][4] = {{a0.x, a0.y, a0.z, a0.w}, {a1.x, a1.y, a1.z, a1.w}};
            float bv[2][4] = {{b0.x, b0.y, b0.z, b0.w}, {b1.x, b1.y, b1.z, b1.w}};
            #pragma unroll
            for (int qa = 0; qa < 2; ++qa)
                #pragma unroll
                for (int i = 0; i < 4; ++i)
                    #pragma unroll
                    for (int qb = 0; qb < 2; ++qb)
                        #pragma unroll
                        for (int j = 0; j < 4; ++j)
                            acc[qa][qb][i][j] = fmaf(av[qa][i], bv[qb][j], acc[qa][qb][i][j]);
        }
        __syncthreads();
    }
    #pragma unroll
    for (int qa = 0; qa < 2; ++qa)
        #pragma unroll
        for (int i = 0; i < 4; ++i) {
            int row = gs * KP + qa * 64 + ty * 4 + i;
            #pragma unroll
            for (int qb = 0; qb < 2; ++qb) {
                int col = gd * KP + qb * 64 + tx * 4;
                #pragma unroll
                for (int j = 0; j < 4; ++j)
                    atomicAdd(&outA[(size_t)row * KT + col + j], acc[qa][qb][i][j]);
            }
        }
}

// ---------------------------------------------------------------------------
extern "C" void kernel_launch(void* const* d_in, const int* in_sizes, int n_in,
                              void* d_out, int out_size, void* d_ws, size_t ws_size,
                              hipStream_t stream) {
    const float* feat   = (const float*)d_in[0];
    const float* W_feat = (const float*)d_in[1];
    const float* b_feat = (const float*)d_in[2];
    const float* W_pool = (const float*)d_in[3];
    const float* b_pool = (const float*)d_in[4];
    const int*   src    = (const int*)d_in[5];
    const int*   dst    = (const int*)d_in[6];
    // d_in[7] = batch_size (16, hardcoded)

    char* w = (char*)d_ws;
    float* xplus = (float*)w;  w += (size_t)N * D * sizeof(float);
    float* hfeat = (float*)w;  w += (size_t)N * D * sizeof(float);
    float* sc    = (float*)w;  w += (size_t)N * KP * sizeof(float);
    int* csr     = (int*)w;    w += (size_t)E * sizeof(int);
    int* bsrc    = (int*)w;    w += (size_t)E * sizeof(int);
    int* bdst    = (int*)w;    w += (size_t)E * sizeof(int);
    int* rowstart= (int*)w;    w += (size_t)(N + 1) * sizeof(int);
    int* boff    = (int*)w;    w += 257 * sizeof(int);
    int* deg     = (int*)w;    w += (size_t)N * sizeof(int);
    int* cursor  = (int*)w;    w += (size_t)N * sizeof(int);
    int* bcnt    = (int*)w;    w += 256 * sizeof(int);
    int* bcur    = (int*)w;    w += 256 * sizeof(int);

    // zero counters (deg, cursor, bcnt, bcur are contiguous) and output
    hipMemsetAsync(deg, 0, ((size_t)2 * N + 512) * sizeof(int), stream);
    hipMemsetAsync(d_out, 0, (size_t)out_size * sizeof(float), stream);

    k_count<<<E / 256, 256, 0, stream>>>(src, dst, deg, bcnt);
    k_scan<<<1, 1024, 0, stream>>>(deg, rowstart, bcnt, boff);
    k_fill<<<E / 256, 256, 0, stream>>>(src, dst, rowstart, cursor, boff, bcur,
                                        csr, bsrc, bdst);
    k_agg<<<N / 4, 256, 0, stream>>>(feat, rowstart, csr, xplus);

    dim3 gf(500, 4);
    k_gemm_feat<<<gf, 256, 0, stream>>>(xplus, W_feat, b_feat, hfeat);
    dim3 gp(32, 16);
    k_gemm_pool<<<gp, 256, 0, stream>>>(xplus, W_pool, b_pool, sc);
    dim3 gh(16, 8, 4);
    k_h<<<gh, 256, 0, stream>>>(sc, hfeat, (float*)d_out + (size_t)KT * KT);
    dim3 ga(256, ADJ_SPLIT);
    k_adj<<<ga, 256, 0, stream>>>(sc, bsrc, bdst, boff, (float*)d_out);
}

// Round 2
// 1721.130 us; speedup vs baseline: 1.5280x; 1.5280x over previous
//
#include <hip/hip_runtime.h>
#include <math.h>

// Problem constants (fixed by the reference)
constexpr int N  = 64000;
constexpr int E  = 1024000;
constexpr int D  = 512;
constexpr int KT = 2048;
constexpr int B  = 16;
constexpr int NP = 4000;   // nodes per graph
constexpr int KP = 128;    // clusters per graph

typedef __attribute__((ext_vector_type(4))) float f32x4;
typedef __attribute__((ext_vector_type(8))) short bf16x8;   // MFMA A/B frag (8 bf16)
typedef __attribute__((ext_vector_type(8))) unsigned short u16x8;

__device__ __forceinline__ unsigned short f2bf(float f) {
    unsigned u = __builtin_bit_cast(unsigned, f);
    return (unsigned short)((u + 0x7FFFu + ((u >> 16) & 1u)) >> 16);
}
__device__ __forceinline__ float bf2f(unsigned short h) {
    unsigned u = (unsigned)h << 16;
    return __builtin_bit_cast(float, u);
}

// ---------------------------------------------------------------------------
// f32 -> bf16 bulk convert (n multiple of 8)
// ---------------------------------------------------------------------------
__global__ __launch_bounds__(256) void k_cvt(const float* __restrict__ in,
                                             unsigned short* __restrict__ out,
                                             long long n) {
    long long i = ((long long)blockIdx.x * 256 + threadIdx.x) * 8;
    if (i >= n) return;
    f32x4 a = *(const f32x4*)&in[i];
    f32x4 b = *(const f32x4*)&in[i + 4];
    u16x8 o;
    o[0] = f2bf(a.x); o[1] = f2bf(a.y); o[2] = f2bf(a.z); o[3] = f2bf(a.w);
    o[4] = f2bf(b.x); o[5] = f2bf(b.y); o[6] = f2bf(b.z); o[7] = f2bf(b.w);
    *(u16x8*)&out[i] = o;
}

// f32 [R][C] -> bf16 [C][R] transpose-convert
__global__ __launch_bounds__(256) void k_transpose(const float* __restrict__ in,
                                                   unsigned short* __restrict__ out,
                                                   int R, int C) {
    __shared__ float tile[32][33];
    int bx = blockIdx.x * 32, by = blockIdx.y * 32;
    int tx = threadIdx.x & 31, ty = threadIdx.x >> 5;   // ty 0..7
    #pragma unroll
    for (int i = 0; i < 32; i += 8)
        if (by + ty + i < R && bx + tx < C)
            tile[ty + i][tx] = in[(size_t)(by + ty + i) * C + bx + tx];
    __syncthreads();
    #pragma unroll
    for (int i = 0; i < 32; i += 8)
        if (bx + ty + i < C && by + tx < R)
            out[(size_t)(bx + ty + i) * R + by + tx] = f2bf(tile[tx][ty + i]);
}

// ---------------------------------------------------------------------------
// CSR / bucket build
// ---------------------------------------------------------------------------
__global__ void k_count(const int* __restrict__ src, const int* __restrict__ dst,
                        int* __restrict__ deg, int* __restrict__ deg2,
                        int* __restrict__ bcnt) {
    int e = blockIdx.x * blockDim.x + threadIdx.x;
    if (e >= E) return;
    int s = src[e], d = dst[e];
    atomicAdd(&deg[d], 1);
    atomicAdd(&deg2[s], 1);
    atomicAdd(&bcnt[(s / NP) * B + d / NP], 1);
}

__global__ void k_scan(const int* __restrict__ deg, int* __restrict__ rowstart,
                       const int* __restrict__ bcnt, int* __restrict__ boff) {
    __shared__ int wsum[16];
    __shared__ int carry;
    int t = threadIdx.x, lane = t & 63, w = t >> 6;
    if (t == 0) carry = 0;
    __syncthreads();
    for (int base = 0; base < N; base += 1024) {
        int v = (base + t < N) ? deg[base + t] : 0;
        int x = v;
        #pragma unroll
        for (int off = 1; off < 64; off <<= 1) {
            int y = __shfl_up(x, off);
            if (lane >= off) x += y;
        }
        if (lane == 63) wsum[w] = x;
        __syncthreads();
        if (t < 16) {
            int s = wsum[t];
            #pragma unroll
            for (int off = 1; off < 16; off <<= 1) {
                int y = __shfl_up(s, off);
                if (t >= off) s += y;
            }
            wsum[t] = s;
        }
        __syncthreads();
        int prev = carry + ((w > 0) ? wsum[w - 1] : 0);
        if (base + t < N) rowstart[base + t] = prev + x - v;
        __syncthreads();
        if (t == 0) carry += wsum[15];
        __syncthreads();
    }
    if (t == 0) {
        rowstart[N] = carry;
        int s = 0;
        for (int i = 0; i < 256; ++i) { boff[i] = s; s += bcnt[i]; }
        boff[256] = s;
    }
}

__global__ void k_fill(const int* __restrict__ src, const int* __restrict__ dst,
                       const int* __restrict__ rowstart, int* __restrict__ cursor,
                       const int* __restrict__ rs2, int* __restrict__ cursor2,
                       const int* __restrict__ boff, int* __restrict__ bcur,
                       int* __restrict__ csr, int* __restrict__ csr2,
                       int* __restrict__ bsrc, int* __restrict__ bdst) {
    int e = blockIdx.x * blockDim.x + threadIdx.x;
    if (e >= E) return;
    int s = src[e], d = dst[e];
    int slot = atomicAdd(&cursor[d], 1);
    csr[rowstart[d] + slot] = s;          // in-edges of d (for mean agg)
    int slot2 = atomicAdd(&cursor2[s], 1);
    csr2[rs2[s] + slot2] = d;             // out-edges of s (unused now, kept cheap)
    int g = (s / NP) * B + d / NP;
    int p = atomicAdd(&bcur[g], 1);
    bsrc[boff[g] + p] = s;
    bdst[boff[g] + p] = d;
}

// ---------------------------------------------------------------------------
// xplus = feat + mean_neighbors(feat), bf16 in / bf16 out, f32 accum
// one wave per node, 16B per lane
// ---------------------------------------------------------------------------
__global__ __launch_bounds__(256) void k_agg(const unsigned short* __restrict__ fb,
                                             const int* __restrict__ rowstart,
                                             const int* __restrict__ csr,
                                             unsigned short* __restrict__ xb) {
    int w = threadIdx.x >> 6, lane = threadIdx.x & 63;
    int node = blockIdx.x * 4 + w;
    int r0 = rowstart[node], r1 = rowstart[node + 1];
    float a[8] = {};
    for (int j = r0; j < r1; ++j) {
        int s = csr[j];
        u16x8 v = *(const u16x8*)&fb[(size_t)s * D + lane * 8];
        #pragma unroll
        for (int q = 0; q < 8; ++q) a[q] += bf2f(v[q]);
    }
    float inv = 1.0f / fmaxf((float)(r1 - r0), 1.0f);
    u16x8 self = *(const u16x8*)&fb[(size_t)node * D + lane * 8];
    u16x8 o;
    #pragma unroll
    for (int q = 0; q < 8; ++q) o[q] = f2bf(bf2f(self[q]) + a[q] * inv);
    *(u16x8*)&xb[(size_t)node * D + lane * 8] = o;
}

// ---------------------------------------------------------------------------
// hfeat = relu(xplus @ W_feat + b) -> bf16.  MFMA, 128x128 tile, 2x2 waves.
// A = xb[m][k], B = Wt[n][k] (pre-transposed weights), both [row][k] in LDS.
// ---------------------------------------------------------------------------
__global__ __launch_bounds__(256) void k_gemm_feat(const unsigned short* __restrict__ Xb,
                                                   const unsigned short* __restrict__ Wt,
                                                   const float* __restrict__ bias,
                                                   unsigned short* __restrict__ Hf) {
    __shared__ unsigned short As[128][72];
    __shared__ unsigned short Bs[128][72];
    int t = threadIdx.x, wid = t >> 6, lane = t & 63;
    int wm = wid >> 1, wn = wid & 1;
    int row0 = blockIdx.x * 128, col0 = blockIdx.y * 128;
    f32x4 acc[4][4] = {};
    for (int k0 = 0; k0 < D; k0 += 64) {
        #pragma unroll
        for (int i = 0; i < 4; ++i) {
            int id = t + i * 256;
            int r = id >> 3, sg = id & 7;
            *(f32x4*)&As[r][sg * 8] = *(const f32x4*)&Xb[(size_t)(row0 + r) * D + k0 + sg * 8];
        }
        #pragma unroll
        for (int i = 0; i < 4; ++i) {
            int id = t + i * 256;
            int r = id >> 3, sg = id & 7;
            *(f32x4*)&Bs[r][sg * 8] = *(const f32x4*)&Wt[(size_t)(col0 + r) * D + k0 + sg * 8];
        }
        __syncthreads();
        #pragma unroll
        for (int ks = 0; ks < 2; ++ks) {
            bf16x8 af[4], bfr[4];
            #pragma unroll
            for (int f = 0; f < 4; ++f)
                af[f] = *(const bf16x8*)&As[wm * 64 + f * 16 + (lane & 15)][ks * 32 + (lane >> 4) * 8];
            #pragma unroll
            for (int f = 0; f < 4; ++f)
                bfr[f] = *(const bf16x8*)&Bs[wn * 64 + f * 16 + (lane & 15)][ks * 32 + (lane >> 4) * 8];
            #pragma unroll
            for (int m = 0; m < 4; ++m)
                #pragma unroll
                for (int n = 0; n < 4; ++n)
                    acc[m][n] = __builtin_amdgcn_mfma_f32_16x16x32_bf16(af[m], bfr[n], acc[m][n], 0, 0, 0);
        }
        __syncthreads();
    }
    float bv[4];
    #pragma unroll
    for (int n = 0; n < 4; ++n) bv[n] = bias[col0 + wn * 64 + n * 16 + (lane & 15)];
    #pragma unroll
    for (int m = 0; m < 4; ++m)
        #pragma unroll
        for (int r = 0; r < 4; ++r) {
            int row = row0 + wm * 64 + m * 16 + (lane >> 4) * 4 + r;
            #pragma unroll
            for (int n = 0; n < 4; ++n) {
                int col = col0 + wn * 64 + n * 16 + (lane & 15);
                float v = fmaxf(acc[m][n][r] + bv[n], 0.f);
                Hf[(size_t)row * D + col] = f2bf(v);
            }
        }
}

// ---------------------------------------------------------------------------
// sc = softmax(relu(xplus @ Wp_g + b_g)) over 128 in-graph cols -> bf16.
// MFMA 128x128 tile, 4 waves stacked in M so each softmax row is wave-local.
// ---------------------------------------------------------------------------
__global__ __launch_bounds__(256) void k_gemm_pool(const unsigned short* __restrict__ Xb,
                                                   const unsigned short* __restrict__ Wpt,
                                                   const float* __restrict__ bp,
                                                   unsigned short* __restrict__ sc) {
    __shared__ unsigned short As[128][72];
    __shared__ unsigned short Bs[128][72];
    int t = threadIdx.x, wid = t >> 6, lane = t & 63;
    int bm = blockIdx.x;      // 0..31
    int g  = blockIdx.y;      // 0..15
    int row0 = g * NP + bm * 128;
    int nrows = NP - bm * 128; if (nrows > 128) nrows = 128;
    int col0 = g * KP;
    f32x4 acc[2][8] = {};
    for (int k0 = 0; k0 < D; k0 += 64) {
        #pragma unroll
        for (int i = 0; i < 4; ++i) {
            int id = t + i * 256;
            int r = id >> 3, sg = id & 7;
            f32x4 v = {0.f, 0.f, 0.f, 0.f};
            if (r < nrows) v = *(const f32x4*)&Xb[(size_t)(row0 + r) * D + k0 + sg * 8];
            *(f32x4*)&As[r][sg * 8] = v;
        }
        #pragma unroll
        for (int i = 0; i < 4; ++i) {
            int id = t + i * 256;
            int r = id >> 3, sg = id & 7;
            *(f32x4*)&Bs[r][sg * 8] = *(const f32x4*)&Wpt[(size_t)(col0 + r) * D + k0 + sg * 8];
        }
        __syncthreads();
        #pragma unroll
        for (int ks = 0; ks < 2; ++ks) {
            bf16x8 af[2], bfr[8];
            #pragma unroll
            for (int m = 0; m < 2; ++m)
                af[m] = *(const bf16x8*)&As[wid * 32 + m * 16 + (lane & 15)][ks * 32 + (lane >> 4) * 8];
            #pragma unroll
            for (int n = 0; n < 8; ++n)
                bfr[n] = *(const bf16x8*)&Bs[n * 16 + (lane & 15)][ks * 32 + (lane >> 4) * 8];
            #pragma unroll
            for (int m = 0; m < 2; ++m)
                #pragma unroll
                for (int n = 0; n < 8; ++n)
                    acc[m][n] = __builtin_amdgcn_mfma_f32_16x16x32_bf16(af[m], bfr[n], acc[m][n], 0, 0, 0);
        }
        __syncthreads();
    }
    float bv[8];
    #pragma unroll
    for (int n = 0; n < 8; ++n) bv[n] = bp[col0 + n * 16 + (lane & 15)];
    #pragma unroll
    for (int m = 0; m < 2; ++m)
        #pragma unroll
        for (int r = 0; r < 4; ++r) {
            float v[8];
            #pragma unroll
            for (int n = 0; n < 8; ++n) v[n] = fmaxf(acc[m][n][r] + bv[n], 0.f);
            float mx = v[0];
            #pragma unroll
            for (int n = 1; n < 8; ++n) mx = fmaxf(mx, v[n]);
            #pragma unroll
            for (int off = 1; off < 16; off <<= 1) mx = fmaxf(mx, __shfl_xor(mx, off));
            float ssum = 0.f;
            #pragma unroll
            for (int n = 0; n < 8; ++n) { v[n] = __expf(v[n] - mx); ssum += v[n]; }
            #pragma unroll
            for (int off = 1; off < 16; off <<= 1) ssum += __shfl_xor(ssum, off);
            float inv = 1.0f / ssum;
            int rowl = wid * 32 + m * 16 + (lane >> 4) * 4 + r;
            if (rowl < nrows) {
                #pragma unroll
                for (int n = 0; n < 8; ++n)
                    sc[(size_t)(row0 + rowl) * KP + n * 16 + (lane & 15)] = f2bf(v[n] * inv);
            }
        }
}

// ---------------------------------------------------------------------------
// h = s^T @ hfeat per graph.  MFMA with transpose-staging of both operands.
// grid (16 graphs, 4 dim-tiles, 8 K-splits); atomicAdd f32 into d_out.
// ---------------------------------------------------------------------------
__global__ __launch_bounds__(256) void k_h(const unsigned short* __restrict__ sc,
                                           const unsigned short* __restrict__ hf,
                                           float* __restrict__ outH) {
    __shared__ unsigned short St[128][72];
    __shared__ unsigned short Ht[128][72];
    int t = threadIdx.x, w = t >> 6, lane = t & 63;
    int g  = blockIdx.x;
    int nt = blockIdx.y;
    int kz = blockIdx.z;
    int n0 = nt * 128;
    int i0 = g * NP + kz * 500, i1 = i0 + 500;
    int c0 = w * 32, el = lane;
    f32x4 acc[2][8] = {};
    for (int kb = i0; kb < i1; kb += 64) {
        int node = kb + el;
        bool ok = node < i1;
        #pragma unroll
        for (int h = 0; h < 4; ++h) {
            u16x8 u = {0,0,0,0,0,0,0,0}, v = {0,0,0,0,0,0,0,0};
            if (ok) {
                u = *(const u16x8*)&sc[(size_t)node * KP + c0 + h * 8];
                v = *(const u16x8*)&hf[(size_t)node * D + n0 + c0 + h * 8];
            }
            #pragma unroll
            for (int q = 0; q < 8; ++q) {
                St[c0 + h * 8 + q][el] = u[q];
                Ht[c0 + h * 8 + q][el] = v[q];
            }
        }
        __syncthreads();
        #pragma unroll
        for (int ks = 0; ks < 2; ++ks) {
            bf16x8 af[2], bfr[8];
            #pragma unroll
            for (int m = 0; m < 2; ++m)
                af[m] = *(const bf16x8*)&St[w * 32 + m * 16 + (lane & 15)][ks * 32 + (lane >> 4) * 8];
            #pragma unroll
            for (int n = 0; n < 8; ++n)
                bfr[n] = *(const bf16x8*)&Ht[n * 16 + (lane & 15)][ks * 32 + (lane >> 4) * 8];
            #pragma unroll
            for (int m = 0; m < 2; ++m)
                #pragma unroll
                for (int n = 0; n < 8; ++n)
                    acc[m][n] = __builtin_amdgcn_mfma_f32_16x16x32_bf16(af[m], bfr[n], acc[m][n], 0, 0, 0);
        }
        __syncthreads();
    }
    #pragma unroll
    for (int m = 0; m < 2; ++m)
        #pragma unroll
        for (int r = 0; r < 4; ++r) {
            int row = g * KP + w * 32 + m * 16 + (lane >> 4) * 4 + r;
            #pragma unroll
            for (int n = 0; n < 8; ++n) {
                int col = n0 + n * 16 + (lane & 15);
                atomicAdd(&outH[(size_t)row * D + col], acc[m][n][r]);
            }
        }
}

// ---------------------------------------------------------------------------
// adj_new bucket (g1,g2) = U^T V over bucket edges, U=sc[src], V=sc[dst].
// MFMA with gather + transpose staging. grid (256 buckets, ADJ_SPLIT).
// ---------------------------------------------------------------------------
constexpr int ADJ_SPLIT = 4;
__global__ __launch_bounds__(256) void k_adj(const unsigned short* __restrict__ sc,
                                             const int* __restrict__ bsrc,
                                             const int* __restrict__ bdst,
                                             const int* __restrict__ boff,
                                             float* __restrict__ outA) {
    __shared__ unsigned short Ut[128][72];
    __shared__ unsigned short Vt[128][72];
    int t = threadIdx.x, w = t >> 6, lane = t & 63;
    int b = blockIdx.x, part = blockIdx.y;
    int g1 = b >> 4, g2 = b & 15;
    int e0 = boff[b], e1 = boff[b + 1], cnt = e1 - e0;
    int s0 = e0 + (int)((long long)cnt * part / ADJ_SPLIT);
    int s1 = e0 + (int)((long long)cnt * (part + 1) / ADJ_SPLIT);
    int c0 = w * 32, el = lane;
    f32x4 acc[2][8] = {};
    for (int kb = s0; kb < s1; kb += 64) {
        int idx = kb + el;
        int sr = -1, dr = -1;
        if (idx < s1) { sr = bsrc[idx]; dr = bdst[idx]; }
        #pragma unroll
        for (int h = 0; h < 4; ++h) {
            u16x8 u = {0,0,0,0,0,0,0,0}, v = {0,0,0,0,0,0,0,0};
            if (sr >= 0) u = *(const u16x8*)&sc[(size_t)sr * KP + c0 + h * 8];
            if (dr >= 0) v = *(const u16x8*)&sc[(size_t)dr * KP + c0 + h * 8];
            #pragma unroll
            for (int q = 0; q < 8; ++q) {
                Ut[c0 + h * 8 + q][el] = u[q];
                Vt[c0 + h * 8 + q][el] = v[q];
            }
        }
        __syncthreads();
        #pragma unroll
        for (int ks = 0; ks < 2; ++ks) {
            bf16x8 af[2], bfr[8];
            #pragma unroll
            for (int m = 0; m < 2; ++m)
                af[m] = *(const bf16x8*)&Ut[w * 32 + m * 16 + (lane & 15)][ks * 32 + (lane >> 4) * 8];
            #pragma unroll
            for (int n = 0; n < 8; ++n)
                bfr[n] = *(const bf16x8*)&Vt[n * 16 + (lane & 15)][ks * 32 + (lane >> 4) * 8];
            #pragma unroll
            for (int m = 0; m < 2; ++m)
                #pragma unroll
                for (int n = 0; n < 8; ++n)
                    acc[m][n] = __builtin_amdgcn_mfma_f32_16x16x32_bf16(af[m], bfr[n], acc[m][n], 0, 0, 0);
        }
        __syncthreads();
    }
    #pragma unroll
    for (int m = 0; m < 2; ++m)
        #pragma unroll
        for (int r = 0; r < 4; ++r) {
            int row = g1 * KP + w * 32 + m * 16 + (lane >> 4) * 4 + r;
            #pragma unroll
            for (int n = 0; n < 8; ++n) {
                int col = g2 * KP + n * 16 + (lane & 15);
                atomicAdd(&outA[(size_t)row * KT + col], acc[m][n][r]);
            }
        }
}

// ---------------------------------------------------------------------------
extern "C" void kernel_launch(void* const* d_in, const int* in_sizes, int n_in,
                              void* d_out, int out_size, void* d_ws, size_t ws_size,
                              hipStream_t stream) {
    const float* feat   = (const float*)d_in[0];
    const float* W_feat = (const float*)d_in[1];
    const float* b_feat = (const float*)d_in[2];
    const float* W_pool = (const float*)d_in[3];
    const float* b_pool = (const float*)d_in[4];
    const int*   src    = (const int*)d_in[5];
    const int*   dst    = (const int*)d_in[6];

    char* w = (char*)d_ws;
    unsigned short* fb  = (unsigned short*)w; w += (size_t)N * D * 2;      // feat bf16
    unsigned short* xb  = (unsigned short*)w; w += (size_t)N * D * 2;      // xplus bf16
    unsigned short* hfb = (unsigned short*)w; w += (size_t)N * D * 2;      // hfeat bf16
    unsigned short* scb = (unsigned short*)w; w += (size_t)N * KP * 2;     // s bf16
    unsigned short* Wt  = (unsigned short*)w; w += (size_t)D * D * 2;      // W_feat^T bf16
    unsigned short* Wpt = (unsigned short*)w; w += (size_t)KT * D * 2;     // W_pool^T bf16
    int* csr      = (int*)w; w += (size_t)E * 4;
    int* csr2     = (int*)w; w += (size_t)E * 4;
    int* bsrc     = (int*)w; w += (size_t)E * 4;
    int* bdst     = (int*)w; w += (size_t)E * 4;
    int* rowstart = (int*)w; w += (size_t)(N + 1) * 4;
    int* rs2      = (int*)w; w += (size_t)(N + 1) * 4;
    int* boff     = (int*)w; w += 257 * 4;
    int* deg      = (int*)w; w += (size_t)N * 4;    // contiguous zero block start
    int* cursor   = (int*)w; w += (size_t)N * 4;
    int* deg2     = (int*)w; w += (size_t)N * 4;
    int* cursor2  = (int*)w; w += (size_t)N * 4;
    int* bcnt     = (int*)w; w += 256 * 4;
    int* bcur     = (int*)w; w += 256 * 4;

    hipMemsetAsync(deg, 0, ((size_t)4 * N + 512) * sizeof(int), stream);
    hipMemsetAsync(d_out, 0, (size_t)out_size * sizeof(float), stream);

    // conversions
    k_cvt<<<(int)(((long long)N * D) / (8 * 256)), 256, 0, stream>>>(feat, fb, (long long)N * D);
    dim3 gt1(D / 32, D / 32);
    k_transpose<<<gt1, 256, 0, stream>>>(W_feat, Wt, D, D);
    dim3 gt2(KT / 32, D / 32);
    k_transpose<<<gt2, 256, 0, stream>>>(W_pool, Wpt, D, KT);

    // graph structure
    k_count<<<E / 256, 256, 0, stream>>>(src, dst, deg, deg2, bcnt);
    k_scan<<<1, 1024, 0, stream>>>(deg, rowstart, bcnt, boff);
    k_scan<<<1, 1024, 0, stream>>>(deg2, rs2, bcnt, boff);
    k_fill<<<E / 256, 256, 0, stream>>>(src, dst, rowstart, cursor, rs2, cursor2,
                                        boff, bcur, csr, csr2, bsrc, bdst);

    // aggregation + GEMMs
    k_agg<<<N / 4, 256, 0, stream>>>(fb, rowstart, csr, xb);
    dim3 gf(N / 128, D / 128);
    k_gemm_feat<<<gf, 256, 0, stream>>>(xb, Wt, b_feat, hfb);
    dim3 gp(32, B);
    k_gemm_pool<<<gp, 256, 0, stream>>>(xb, Wpt, b_pool, scb);
    dim3 gh(B, D / 128, 8);
    k_h<<<gh, 256, 0, stream>>>(scb, hfb, (float*)d_out + (size_t)KT * KT);
    dim3 ga(256, ADJ_SPLIT);
    k_adj<<<ga, 256, 0, stream>>>(scb, bsrc, bdst, boff, (float*)d_out);
}

// Round 3
// 628.161 us; speedup vs baseline: 4.1867x; 2.7400x over previous
//
#include <hip/hip_runtime.h>
#include <math.h>

// Problem constants (fixed by the reference)
constexpr int N  = 64000;
constexpr int E  = 1024000;
constexpr int D  = 512;
constexpr int KT = 2048;
constexpr int B  = 16;
constexpr int NP = 4000;   // nodes per graph
constexpr int KP = 128;    // clusters per graph
constexpr int NR = N / 256;        // 250 dst-ranges of 256 nodes
constexpr int EPB = 1024;          // edges per partition block
constexpr int NPB = E / EPB;       // 1000 partition blocks

typedef __attribute__((ext_vector_type(4))) float f32x4;
typedef __attribute__((ext_vector_type(8))) short bf16x8;   // MFMA A/B frag (8 bf16)
typedef __attribute__((ext_vector_type(8))) unsigned short u16x8;

__device__ __forceinline__ unsigned short f2bf(float f) {
    unsigned u = __builtin_bit_cast(unsigned, f);
    return (unsigned short)((u + 0x7FFFu + ((u >> 16) & 1u)) >> 16);
}
__device__ __forceinline__ float bf2f(unsigned short h) {
    unsigned u = (unsigned)h << 16;
    return __builtin_bit_cast(float, u);
}

// block-wide (256 thr) inclusive scan; ws is 4-int LDS scratch
__device__ __forceinline__ int block_incl_scan(int v, int* ws) {
    int t = threadIdx.x, lane = t & 63, w = t >> 6;
    int x = v;
    #pragma unroll
    for (int off = 1; off < 64; off <<= 1) {
        int y = __shfl_up(x, off);
        if (lane >= off) x += y;
    }
    if (lane == 63) ws[w] = x;
    __syncthreads();
    if (t < 4) {
        int s = ws[t];
        #pragma unroll
        for (int off = 1; off < 4; off <<= 1) {
            int y = __shfl_up(s, off);
            if (t >= off) s += y;
        }
        ws[t] = s;
    }
    __syncthreads();
    return x + (w > 0 ? ws[w - 1] : 0);
}

// ---------------------------------------------------------------------------
// f32 -> bf16 bulk convert (n multiple of 8)
// ---------------------------------------------------------------------------
__global__ __launch_bounds__(256) void k_cvt(const float* __restrict__ in,
                                             unsigned short* __restrict__ out,
                                             long long n) {
    long long i = ((long long)blockIdx.x * 256 + threadIdx.x) * 8;
    if (i >= n) return;
    f32x4 a = *(const f32x4*)&in[i];
    f32x4 b = *(const f32x4*)&in[i + 4];
    u16x8 o;
    o[0] = f2bf(a.x); o[1] = f2bf(a.y); o[2] = f2bf(a.z); o[3] = f2bf(a.w);
    o[4] = f2bf(b.x); o[5] = f2bf(b.y); o[6] = f2bf(b.z); o[7] = f2bf(b.w);
    *(u16x8*)&out[i] = o;
}

// f32 [R][C] -> bf16 [C][R] transpose-convert
__global__ __launch_bounds__(256) void k_transpose(const float* __restrict__ in,
                                                   unsigned short* __restrict__ out,
                                                   int R, int C) {
    __shared__ float tile[32][33];
    int bx = blockIdx.x * 32, by = blockIdx.y * 32;
    int tx = threadIdx.x & 31, ty = threadIdx.x >> 5;   // ty 0..7
    #pragma unroll
    for (int i = 0; i < 32; i += 8)
        if (by + ty + i < R && bx + tx < C)
            tile[ty + i][tx] = in[(size_t)(by + ty + i) * C + bx + tx];
    __syncthreads();
    #pragma unroll
    for (int i = 0; i < 32; i += 8)
        if (bx + ty + i < C && by + tx < R)
            out[(size_t)(bx + ty + i) * R + by + tx] = f2bf(tile[tx][ty + i]);
}

// ---------------------------------------------------------------------------
// Graph build: LDS-binned histograms / partitions (no scattered 4B stores)
// ---------------------------------------------------------------------------
__global__ __launch_bounds__(256) void k_count2(const int* __restrict__ src,
                                                const int* __restrict__ dst,
                                                int* __restrict__ bcnt,
                                                int* __restrict__ rcnt) {
    __shared__ int hb[256];
    __shared__ int hr[256];
    int t = threadIdx.x;
    hb[t] = 0; hr[t] = 0;
    __syncthreads();
    int e0 = blockIdx.x * EPB;
    #pragma unroll
    for (int i = 0; i < EPB / 256; ++i) {
        int e = e0 + t + i * 256;
        int s = src[e], d = dst[e];
        atomicAdd(&hb[(s / NP) * B + d / NP], 1);
        atomicAdd(&hr[d >> 8], 1);
    }
    __syncthreads();
    if (hb[t]) atomicAdd(&bcnt[t], hb[t]);
    if (t < NR && hr[t]) atomicAdd(&rcnt[t], hr[t]);
}

__global__ __launch_bounds__(256) void k_scan2(const int* __restrict__ bcnt,
                                               int* __restrict__ boff, int* __restrict__ bcur,
                                               const int* __restrict__ rcnt,
                                               int* __restrict__ roff, int* __restrict__ rcur,
                                               int* __restrict__ rowstart) {
    __shared__ int ws[4];
    int t = threadIdx.x;
    int v1 = bcnt[t];
    int incl1 = block_incl_scan(v1, ws);
    boff[t] = incl1 - v1;
    bcur[t] = incl1 - v1;
    if (t == 255) boff[256] = incl1;
    __syncthreads();
    int v2 = (t < NR) ? rcnt[t] : 0;
    int incl2 = block_incl_scan(v2, ws);
    if (t < NR) { roff[t] = incl2 - v2; rcur[t] = incl2 - v2; }
    if (t == 0) { roff[NR] = E; rowstart[N] = E; }
}

// partition edges by dst>>8 into int2 pairs (LDS rank + block reservation)
__global__ __launch_bounds__(256) void k_part1(const int* __restrict__ src,
                                               const int* __restrict__ dst,
                                               int* __restrict__ rcur,
                                               int2* __restrict__ out) {
    __shared__ int h[256];
    int t = threadIdx.x;
    h[t] = 0;
    __syncthreads();
    int e0 = blockIdx.x * EPB;
    int bin[EPB / 256], rank[EPB / 256], sv[EPB / 256], dv[EPB / 256];
    #pragma unroll
    for (int i = 0; i < EPB / 256; ++i) {
        int e = e0 + t + i * 256;
        sv[i] = src[e]; dv[i] = dst[e];
        bin[i] = dv[i] >> 8;
        rank[i] = atomicAdd(&h[bin[i]], 1);
    }
    __syncthreads();
    int c = h[t], base = 0;
    if (t < NR && c) base = atomicAdd(&rcur[t], c);
    h[t] = base;
    __syncthreads();
    #pragma unroll
    for (int i = 0; i < EPB / 256; ++i)
        out[h[bin[i]] + rank[i]] = int2{sv[i], dv[i]};
}

// per 256-node range: exact-dst counting sort -> rowstart + csr
__global__ __launch_bounds__(256) void k_part2(const int2* __restrict__ pairs,
                                               const int* __restrict__ roff,
                                               int* __restrict__ rowstart,
                                               int* __restrict__ csr) {
    __shared__ int h[256];
    __shared__ int ws[4];
    int t = threadIdx.x;
    int r = blockIdx.x;
    int p0 = roff[r], p1 = roff[r + 1];
    h[t] = 0;
    __syncthreads();
    for (int p = p0 + t; p < p1; p += 256)
        atomicAdd(&h[pairs[p].y & 255], 1);
    __syncthreads();
    int v = h[t];
    int incl = block_incl_scan(v, ws);
    int start = p0 + incl - v;
    __syncthreads();
    h[t] = start;
    rowstart[r * 256 + t] = start;
    __syncthreads();
    for (int p = p0 + t; p < p1; p += 256) {
        int2 e = pairs[p];
        int pos = atomicAdd(&h[e.y & 255], 1);
        csr[pos] = e.x;
    }
}

// partition edges by (g_src, g_dst) into int2 pairs for k_adj
__global__ __launch_bounds__(256) void k_bucket(const int* __restrict__ src,
                                                const int* __restrict__ dst,
                                                int* __restrict__ bcur,
                                                int2* __restrict__ out) {
    __shared__ int h[256];
    int t = threadIdx.x;
    h[t] = 0;
    __syncthreads();
    int e0 = blockIdx.x * EPB;
    int bin[EPB / 256], rank[EPB / 256], sv[EPB / 256], dv[EPB / 256];
    #pragma unroll
    for (int i = 0; i < EPB / 256; ++i) {
        int e = e0 + t + i * 256;
        sv[i] = src[e]; dv[i] = dst[e];
        bin[i] = (sv[i] / NP) * B + dv[i] / NP;
        rank[i] = atomicAdd(&h[bin[i]], 1);
    }
    __syncthreads();
    int c = h[t], base = 0;
    if (c) base = atomicAdd(&bcur[t], c);
    h[t] = base;
    __syncthreads();
    #pragma unroll
    for (int i = 0; i < EPB / 256; ++i)
        out[h[bin[i]] + rank[i]] = int2{sv[i], dv[i]};
}

// ---------------------------------------------------------------------------
// xplus = feat + mean_neighbors(feat), bf16 in / bf16 out, f32 accum
// one wave per node, 16B per lane
// ---------------------------------------------------------------------------
__global__ __launch_bounds__(256) void k_agg(const unsigned short* __restrict__ fb,
                                             const int* __restrict__ rowstart,
                                             const int* __restrict__ csr,
                                             unsigned short* __restrict__ xb) {
    int w = threadIdx.x >> 6, lane = threadIdx.x & 63;
    int node = blockIdx.x * 4 + w;
    int r0 = rowstart[node], r1 = rowstart[node + 1];
    float a[8] = {};
    for (int j = r0; j < r1; ++j) {
        int s = csr[j];
        u16x8 v = *(const u16x8*)&fb[(size_t)s * D + lane * 8];
        #pragma unroll
        for (int q = 0; q < 8; ++q) a[q] += bf2f(v[q]);
    }
    float inv = 1.0f / fmaxf((float)(r1 - r0), 1.0f);
    u16x8 self = *(const u16x8*)&fb[(size_t)node * D + lane * 8];
    u16x8 o;
    #pragma unroll
    for (int q = 0; q < 8; ++q) o[q] = f2bf(bf2f(self[q]) + a[q] * inv);
    *(u16x8*)&xb[(size_t)node * D + lane * 8] = o;
}

// ---------------------------------------------------------------------------
// hfeat = relu(xplus @ W_feat + b) -> bf16.  MFMA, 128x128 tile, 2x2 waves.
// ---------------------------------------------------------------------------
__global__ __launch_bounds__(256) void k_gemm_feat(const unsigned short* __restrict__ Xb,
                                                   const unsigned short* __restrict__ Wt,
                                                   const float* __restrict__ bias,
                                                   unsigned short* __restrict__ Hf) {
    __shared__ unsigned short As[128][72];
    __shared__ unsigned short Bs[128][72];
    int t = threadIdx.x, wid = t >> 6, lane = t & 63;
    int wm = wid >> 1, wn = wid & 1;
    int row0 = blockIdx.x * 128, col0 = blockIdx.y * 128;
    f32x4 acc[4][4] = {};
    for (int k0 = 0; k0 < D; k0 += 64) {
        #pragma unroll
        for (int i = 0; i < 4; ++i) {
            int id = t + i * 256;
            int r = id >> 3, sg = id & 7;
            *(f32x4*)&As[r][sg * 8] = *(const f32x4*)&Xb[(size_t)(row0 + r) * D + k0 + sg * 8];
        }
        #pragma unroll
        for (int i = 0; i < 4; ++i) {
            int id = t + i * 256;
            int r = id >> 3, sg = id & 7;
            *(f32x4*)&Bs[r][sg * 8] = *(const f32x4*)&Wt[(size_t)(col0 + r) * D + k0 + sg * 8];
        }
        __syncthreads();
        #pragma unroll
        for (int ks = 0; ks < 2; ++ks) {
            bf16x8 af[4], bfr[4];
            #pragma unroll
            for (int f = 0; f < 4; ++f)
                af[f] = *(const bf16x8*)&As[wm * 64 + f * 16 + (lane & 15)][ks * 32 + (lane >> 4) * 8];
            #pragma unroll
            for (int f = 0; f < 4; ++f)
                bfr[f] = *(const bf16x8*)&Bs[wn * 64 + f * 16 + (lane & 15)][ks * 32 + (lane >> 4) * 8];
            #pragma unroll
            for (int m = 0; m < 4; ++m)
                #pragma unroll
                for (int n = 0; n < 4; ++n)
                    acc[m][n] = __builtin_amdgcn_mfma_f32_16x16x32_bf16(af[m], bfr[n], acc[m][n], 0, 0, 0);
        }
        __syncthreads();
    }
    float bv[4];
    #pragma unroll
    for (int n = 0; n < 4; ++n) bv[n] = bias[col0 + wn * 64 + n * 16 + (lane & 15)];
    #pragma unroll
    for (int m = 0; m < 4; ++m)
        #pragma unroll
        for (int r = 0; r < 4; ++r) {
            int row = row0 + wm * 64 + m * 16 + (lane >> 4) * 4 + r;
            #pragma unroll
            for (int n = 0; n < 4; ++n) {
                int col = col0 + wn * 64 + n * 16 + (lane & 15);
                float v = fmaxf(acc[m][n][r] + bv[n], 0.f);
                Hf[(size_t)row * D + col] = f2bf(v);
            }
        }
}

// ---------------------------------------------------------------------------
// sc = softmax(relu(xplus @ Wp_g + b_g)) over 128 in-graph cols -> bf16.
// ---------------------------------------------------------------------------
__global__ __launch_bounds__(256) void k_gemm_pool(const unsigned short* __restrict__ Xb,
                                                   const unsigned short* __restrict__ Wpt,
                                                   const float* __restrict__ bp,
                                                   unsigned short* __restrict__ sc) {
    __shared__ unsigned short As[128][72];
    __shared__ unsigned short Bs[128][72];
    int t = threadIdx.x, wid = t >> 6, lane = t & 63;
    int bm = blockIdx.x;      // 0..31
    int g  = blockIdx.y;      // 0..15
    int row0 = g * NP + bm * 128;
    int nrows = NP - bm * 128; if (nrows > 128) nrows = 128;
    int col0 = g * KP;
    f32x4 acc[2][8] = {};
    for (int k0 = 0; k0 < D; k0 += 64) {
        #pragma unroll
        for (int i = 0; i < 4; ++i) {
            int id = t + i * 256;
            int r = id >> 3, sg = id & 7;
            f32x4 v = {0.f, 0.f, 0.f, 0.f};
            if (r < nrows) v = *(const f32x4*)&Xb[(size_t)(row0 + r) * D + k0 + sg * 8];
            *(f32x4*)&As[r][sg * 8] = v;
        }
        #pragma unroll
        for (int i = 0; i < 4; ++i) {
            int id = t + i * 256;
            int r = id >> 3, sg = id & 7;
            *(f32x4*)&Bs[r][sg * 8] = *(const f32x4*)&Wpt[(size_t)(col0 + r) * D + k0 + sg * 8];
        }
        __syncthreads();
        #pragma unroll
        for (int ks = 0; ks < 2; ++ks) {
            bf16x8 af[2], bfr[8];
            #pragma unroll
            for (int m = 0; m < 2; ++m)
                af[m] = *(const bf16x8*)&As[wid * 32 + m * 16 + (lane & 15)][ks * 32 + (lane >> 4) * 8];
            #pragma unroll
            for (int n = 0; n < 8; ++n)
                bfr[n] = *(const bf16x8*)&Bs[n * 16 + (lane & 15)][ks * 32 + (lane >> 4) * 8];
            #pragma unroll
            for (int m = 0; m < 2; ++m)
                #pragma unroll
                for (int n = 0; n < 8; ++n)
                    acc[m][n] = __builtin_amdgcn_mfma_f32_16x16x32_bf16(af[m], bfr[n], acc[m][n], 0, 0, 0);
        }
        __syncthreads();
    }
    float bv[8];
    #pragma unroll
    for (int n = 0; n < 8; ++n) bv[n] = bp[col0 + n * 16 + (lane & 15)];
    #pragma unroll
    for (int m = 0; m < 2; ++m)
        #pragma unroll
        for (int r = 0; r < 4; ++r) {
            float v[8];
            #pragma unroll
            for (int n = 0; n < 8; ++n) v[n] = fmaxf(acc[m][n][r] + bv[n], 0.f);
            float mx = v[0];
            #pragma unroll
            for (int n = 1; n < 8; ++n) mx = fmaxf(mx, v[n]);
            #pragma unroll
            for (int off = 1; off < 16; off <<= 1) mx = fmaxf(mx, __shfl_xor(mx, off));
            float ssum = 0.f;
            #pragma unroll
            for (int n = 0; n < 8; ++n) { v[n] = __expf(v[n] - mx); ssum += v[n]; }
            #pragma unroll
            for (int off = 1; off < 16; off <<= 1) ssum += __shfl_xor(ssum, off);
            float inv = 1.0f / ssum;
            int rowl = wid * 32 + m * 16 + (lane >> 4) * 4 + r;
            if (rowl < nrows) {
                #pragma unroll
                for (int n = 0; n < 8; ++n)
                    sc[(size_t)(row0 + rowl) * KP + n * 16 + (lane & 15)] = f2bf(v[n] * inv);
            }
        }
}

// ---------------------------------------------------------------------------
// h = s^T @ hfeat per graph.  MFMA with transpose-staging of both operands.
// ---------------------------------------------------------------------------
__global__ __launch_bounds__(256) void k_h(const unsigned short* __restrict__ sc,
                                           const unsigned short* __restrict__ hf,
                                           float* __restrict__ outH) {
    __shared__ unsigned short St[128][72];
    __shared__ unsigned short Ht[128][72];
    int t = threadIdx.x, w = t >> 6, lane = t & 63;
    int g  = blockIdx.x;
    int nt = blockIdx.y;
    int kz = blockIdx.z;
    int n0 = nt * 128;
    int i0 = g * NP + kz * 500, i1 = i0 + 500;
    int c0 = w * 32, el = lane;
    f32x4 acc[2][8] = {};
    for (int kb = i0; kb < i1; kb += 64) {
        int node = kb + el;
        bool ok = node < i1;
        #pragma unroll
        for (int h = 0; h < 4; ++h) {
            u16x8 u = {0,0,0,0,0,0,0,0}, v = {0,0,0,0,0,0,0,0};
            if (ok) {
                u = *(const u16x8*)&sc[(size_t)node * KP + c0 + h * 8];
                v = *(const u16x8*)&hf[(size_t)node * D + n0 + c0 + h * 8];
            }
            #pragma unroll
            for (int q = 0; q < 8; ++q) {
                St[c0 + h * 8 + q][el] = u[q];
                Ht[c0 + h * 8 + q][el] = v[q];
            }
        }
        __syncthreads();
        #pragma unroll
        for (int ks = 0; ks < 2; ++ks) {
            bf16x8 af[2], bfr[8];
            #pragma unroll
            for (int m = 0; m < 2; ++m)
                af[m] = *(const bf16x8*)&St[w * 32 + m * 16 + (lane & 15)][ks * 32 + (lane >> 4) * 8];
            #pragma unroll
            for (int n = 0; n < 8; ++n)
                bfr[n] = *(const bf16x8*)&Ht[n * 16 + (lane & 15)][ks * 32 + (lane >> 4) * 8];
            #pragma unroll
            for (int m = 0; m < 2; ++m)
                #pragma unroll
                for (int n = 0; n < 8; ++n)
                    acc[m][n] = __builtin_amdgcn_mfma_f32_16x16x32_bf16(af[m], bfr[n], acc[m][n], 0, 0, 0);
        }
        __syncthreads();
    }
    #pragma unroll
    for (int m = 0; m < 2; ++m)
        #pragma unroll
        for (int r = 0; r < 4; ++r) {
            int row = g * KP + w * 32 + m * 16 + (lane >> 4) * 4 + r;
            #pragma unroll
            for (int n = 0; n < 8; ++n) {
                int col = n0 + n * 16 + (lane & 15);
                atomicAdd(&outH[(size_t)row * D + col], acc[m][n][r]);
            }
        }
}

// ---------------------------------------------------------------------------
// adj_new bucket (g1,g2) = U^T V over bucket edges, U=sc[src], V=sc[dst].
// ---------------------------------------------------------------------------
constexpr int ADJ_SPLIT = 4;
__global__ __launch_bounds__(256) void k_adj(const unsigned short* __restrict__ sc,
                                             const int2* __restrict__ bpairs,
                                             const int* __restrict__ boff,
                                             float* __restrict__ outA) {
    __shared__ unsigned short Ut[128][72];
    __shared__ unsigned short Vt[128][72];
    int t = threadIdx.x, w = t >> 6, lane = t & 63;
    int b = blockIdx.x, part = blockIdx.y;
    int g1 = b >> 4, g2 = b & 15;
    int e0 = boff[b], e1 = boff[b + 1], cnt = e1 - e0;
    int s0 = e0 + (int)((long long)cnt * part / ADJ_SPLIT);
    int s1 = e0 + (int)((long long)cnt * (part + 1) / ADJ_SPLIT);
    int c0 = w * 32, el = lane;
    f32x4 acc[2][8] = {};
    for (int kb = s0; kb < s1; kb += 64) {
        int idx = kb + el;
        int sr = -1, dr = -1;
        if (idx < s1) { int2 e = bpairs[idx]; sr = e.x; dr = e.y; }
        #pragma unroll
        for (int h = 0; h < 4; ++h) {
            u16x8 u = {0,0,0,0,0,0,0,0}, v = {0,0,0,0,0,0,0,0};
            if (sr >= 0) u = *(const u16x8*)&sc[(size_t)sr * KP + c0 + h * 8];
            if (dr >= 0) v = *(const u16x8*)&sc[(size_t)dr * KP + c0 + h * 8];
            #pragma unroll
            for (int q = 0; q < 8; ++q) {
                Ut[c0 + h * 8 + q][el] = u[q];
                Vt[c0 + h * 8 + q][el] = v[q];
            }
        }
        __syncthreads();
        #pragma unroll
        for (int ks = 0; ks < 2; ++ks) {
            bf16x8 af[2], bfr[8];
            #pragma unroll
            for (int m = 0; m < 2; ++m)
                af[m] = *(const bf16x8*)&Ut[w * 32 + m * 16 + (lane & 15)][ks * 32 + (lane >> 4) * 8];
            #pragma unroll
            for (int n = 0; n < 8; ++n)
                bfr[n] = *(const bf16x8*)&Vt[n * 16 + (lane & 15)][ks * 32 + (lane >> 4) * 8];
            #pragma unroll
            for (int m = 0; m < 2; ++m)
                #pragma unroll
                for (int n = 0; n < 8; ++n)
                    acc[m][n] = __builtin_amdgcn_mfma_f32_16x16x32_bf16(af[m], bfr[n], acc[m][n], 0, 0, 0);
        }
        __syncthreads();
    }
    #pragma unroll
    for (int m = 0; m < 2; ++m)
        #pragma unroll
        for (int r = 0; r < 4; ++r) {
            int row = g1 * KP + w * 32 + m * 16 + (lane >> 4) * 4 + r;
            #pragma unroll
            for (int n = 0; n < 8; ++n) {
                int col = g2 * KP + n * 16 + (lane & 15);
                atomicAdd(&outA[(size_t)row * KT + col], acc[m][n][r]);
            }
        }
}

// ---------------------------------------------------------------------------
extern "C" void kernel_launch(void* const* d_in, const int* in_sizes, int n_in,
                              void* d_out, int out_size, void* d_ws, size_t ws_size,
                              hipStream_t stream) {
    const float* feat   = (const float*)d_in[0];
    const float* W_feat = (const float*)d_in[1];
    const float* b_feat = (const float*)d_in[2];
    const float* W_pool = (const float*)d_in[3];
    const float* b_pool = (const float*)d_in[4];
    const int*   src    = (const int*)d_in[5];
    const int*   dst    = (const int*)d_in[6];

    char* w = (char*)d_ws;
    unsigned short* fb  = (unsigned short*)w; w += (size_t)N * D * 2;      // feat bf16
    unsigned short* xb  = (unsigned short*)w; w += (size_t)N * D * 2;      // xplus bf16
    unsigned short* hfb = (unsigned short*)w; w += (size_t)N * D * 2;      // hfeat bf16
    unsigned short* scb = (unsigned short*)w; w += (size_t)N * KP * 2;     // s bf16
    unsigned short* Wt  = (unsigned short*)w; w += (size_t)D * D * 2;      // W_feat^T
    unsigned short* Wpt = (unsigned short*)w; w += (size_t)KT * D * 2;     // W_pool^T
    int2* pairs1  = (int2*)w; w += (size_t)E * 8;    // dst-range partitioned edges
    int2* bpairs  = (int2*)w; w += (size_t)E * 8;    // (gs,gd) bucketed edges
    int*  csr     = (int*)w;  w += (size_t)E * 4;    // srcs sorted by dst
    int*  rowstart= (int*)w;  w += (size_t)(N + 1) * 4;
    int*  roff    = (int*)w;  w += (NR + 1) * 4;
    int*  rcur    = (int*)w;  w += NR * 4;
    int*  boff    = (int*)w;  w += 257 * 4;
    int*  bcur    = (int*)w;  w += 256 * 4;
    int*  bcnt    = (int*)w;  w += 256 * 4;          // contiguous with rcnt for memset
    int*  rcnt    = (int*)w;  w += 256 * 4;

    hipMemsetAsync(bcnt, 0, 512 * sizeof(int), stream);
    hipMemsetAsync(d_out, 0, (size_t)out_size * sizeof(float), stream);

    // conversions
    k_cvt<<<(int)(((long long)N * D) / (8 * 256)), 256, 0, stream>>>(feat, fb, (long long)N * D);
    dim3 gt1(D / 32, D / 32);
    k_transpose<<<gt1, 256, 0, stream>>>(W_feat, Wt, D, D);
    dim3 gt2(KT / 32, D / 32);
    k_transpose<<<gt2, 256, 0, stream>>>(W_pool, Wpt, D, KT);

    // graph structure (partition pipeline, coalesced writes)
    k_count2<<<NPB, 256, 0, stream>>>(src, dst, bcnt, rcnt);
    k_scan2<<<1, 256, 0, stream>>>(bcnt, boff, bcur, rcnt, roff, rcur, rowstart);
    k_part1<<<NPB, 256, 0, stream>>>(src, dst, rcur, pairs1);
    k_part2<<<NR, 256, 0, stream>>>(pairs1, roff, rowstart, csr);
    k_bucket<<<NPB, 256, 0, stream>>>(src, dst, bcur, bpairs);

    // aggregation + GEMMs
    k_agg<<<N / 4, 256, 0, stream>>>(fb, rowstart, csr, xb);
    dim3 gf(N / 128, D / 128);
    k_gemm_feat<<<gf, 256, 0, stream>>>(xb, Wt, b_feat, hfb);
    dim3 gp(32, B);
    k_gemm_pool<<<gp, 256, 0, stream>>>(xb, Wpt, b_pool, scb);
    dim3 gh(B, D / 128, 8);
    k_h<<<gh, 256, 0, stream>>>(scb, hfb, (float*)d_out + (size_t)KT * KT);
    dim3 ga(256, ADJ_SPLIT);
    k_adj<<<ga, 256, 0, stream>>>(scb, bpairs, boff, (float*)d_out);
}